// Round 7
// baseline (426.704 us; speedup 1.0000x reference)
//
#include <hip/hip_runtime.h>
#include <stdint.h>

#define T_ 10
#define B_ 4
#define C_ 384
#define N_ 384
#define H_ 12
#define CN_ 147456      // C_*N_
#define TBCN_ 5898240   // T_*B_*C_*N_
#define BCN_ 589824     // B_*C_*N_
#define PKN_ 184320     // 40*12*384  (packed words per q/k/v array)

typedef _Float16 f16x8 __attribute__((ext_vector_type(8)));
typedef float f32x16 __attribute__((ext_vector_type(16)));

#define VMCNT(N) asm volatile("s_waitcnt vmcnt(" #N ")" ::: "memory")
#define SBAR()   __builtin_amdgcn_s_barrier()
#define SCHEDB() __builtin_amdgcn_sched_barrier(0)

#define INV2048 4.8828125e-4f
#define H_MIN_NORMAL 6.103515625e-05f

// Exact-ish 2-level fp16 split: v = H0 + H1*2^-11, H1 stored pre-scaled by
// 2^11 so it is never denormal for the magnitudes seen here. If |v| is below
// fp16 min-normal, everything goes into the scaled level (H0=0), so
// correctness never depends on MFMA denormal-input behavior.
__device__ inline void split2h(float v, uint16_t* h0, uint16_t* h1) {
  _Float16 H0 = (fabsf(v) < H_MIN_NORMAL) ? (_Float16)0.0f : (_Float16)v;  // RNE
  const float r = (v - (float)H0) * 2048.0f;
  _Float16 H1 = (_Float16)r;
  *h0 = __builtin_bit_cast(uint16_t, H0);
  *h1 = __builtin_bit_cast(uint16_t, H1);
}

// async global->LDS, 16B per lane; LDS dest must be wave-uniform base + lane*16
__device__ inline void gload_lds16(const void* g, void* l) {
  __builtin_amdgcn_global_load_lds(
      (const __attribute__((address_space(1))) uint32_t*)g,
      (__attribute__((address_space(3))) uint32_t*)l, 16, 0, 0);
}

// ===========================================================================
// Weight split: 8 convs (Sq,Sk,Sv,Tq,Tk,Tv,Sproj,Tproj) -> 2 fp16 levels
// Wsplit[(conv*2+v)*147456 + oc*384 + k].
// ===========================================================================
__global__ __launch_bounds__(256) void wsplit_kernel(
    const float* __restrict__ sW, const float* __restrict__ tW,
    uint16_t* __restrict__ Wsplit)
{
  const int idx = blockIdx.x * 256 + threadIdx.x;   // < 8*147456
  const int conv = idx / 147456, rem = idx % 147456;
  const float* src;
  switch (conv) {
    case 0: src = sW;          break;
    case 1: src = sW + CN_;    break;
    case 2: src = sW + 2*CN_;  break;
    case 3: src = tW;          break;
    case 4: src = tW + CN_;    break;
    case 5: src = tW + 2*CN_;  break;
    case 6: src = sW + 3*CN_;  break;
    default: src = tW + 3*CN_; break;
  }
  uint16_t h0, h1;
  split2h(src[rem], &h0, &h1);
  Wsplit[(size_t)(conv*2 + 0)*147456 + rem] = h0;
  Wsplit[(size_t)(conv*2 + 1)*147456 + rem] = h1;
}

// Split x,y into 2 fp16 levels, TRANSPOSED: XT[inp][v][tb][n][k].
__global__ __launch_bounds__(256) void xsplit_kernel(
    const float* __restrict__ x, const float* __restrict__ y,
    uint16_t* __restrict__ XT)
{
  const int kt = blockIdx.x;            // 0..11 -> k0
  const int nt = blockIdx.y;            // 0..2  -> n0
  const int z  = blockIdx.z;            // 0..79: inp*40+tb
  const int inp = z / 40, tb = z % 40;
  const float* in = (inp ? y : x) + (size_t)tb * CN_;
  const int k0 = kt * 32, n0 = nt * 128;
  __shared__ uint16_t Ls[2][32][132];
  const int tid = threadIdx.x;
  const int kr = tid >> 3, nc = (tid & 7) * 16;
  #pragma unroll
  for (int q = 0; q < 4; q++) {
    const float4 f = *(const float4*)(in + (size_t)(k0 + kr)*384 + n0 + nc + q*4);
    const float vv[4] = {f.x, f.y, f.z, f.w};
    #pragma unroll
    for (int e = 0; e < 4; e++) {
      uint16_t h0, h1;
      split2h(vv[e], &h0, &h1);
      Ls[0][kr][nc + q*4 + e] = h0;
      Ls[1][kr][nc + q*4 + e] = h1;
    }
  }
  __syncthreads();
  {
    const int v = tid >> 7, n = tid & 127;    // 256 threads = 2 levels x 128 n
    uint16_t tmp[32];
    #pragma unroll
    for (int k = 0; k < 32; k++) tmp[k] = Ls[v][k][n];
    uint4* dst = (uint4*)(XT + (((size_t)(inp*2 + v)*40 + tb)*384 + (n0 + n))*384 + k0);
    const uint4* s = (const uint4*)tmp;
    dst[0] = s[0]; dst[1] = s[1]; dst[2] = s[2]; dst[3] = s[3];
  }
}

// ===========================================================================
// conv1 via MFMA: 6 convs, 3-product 2-level-fp16 GEMM + BN + LIF ->
// bit-packed spikes. 128x128 tile, 4 waves, BK=16, 3-buffer counted-vmcnt
// pipeline (T3+T4) + setprio (T5). accA = X0W0; accB = X0W1s + X1sW0;
// z = (accA + accB/2048)*g + b.
// Grid: 1-D 2160 XCD-swizzled (T1).
// ===========================================================================
__global__ __launch_bounds__(256) void conv1_mfma(
    const uint16_t* __restrict__ Wsplit, const uint16_t* __restrict__ XT,
    const float* __restrict__ sg, const float* __restrict__ sb,
    const float* __restrict__ tg, const float* __restrict__ tb_,
    uint32_t* __restrict__ PSq, uint32_t* __restrict__ PSk, uint32_t* __restrict__ PSv,
    uint32_t* __restrict__ PTq, uint32_t* __restrict__ PTk, uint32_t* __restrict__ PTv)
{
  // ---- XCD-aware bijective remap (2160 = 8 XCD x 270; 270 = 3 ntile x 18 cm x 5 tb) ----
  const int bid = blockIdx.x;
  const int xcd = bid & 7, pos = bid >> 3;     // pos in [0,270)
  const int ntile = pos / 90;
  const int r = pos % 90;
  const int cm = r / 5;                        // (conv,mt) in [0,18)
  const int tb_i = xcd * 5 + (r % 5);          // [0,40)
  const int conv = cm / 3, row0 = (cm % 3) * 128, n0 = ntile * 128;
  const int t = tb_i >> 2, b = tb_i & 3;
  const int slot = (conv < 3) ? conv : conv - 3;
  const int inp = (conv == 0 || conv == 3) ? 0 : 1;

  __shared__ uint8_t lds[49152];                 // 3 x (A 8KB + B 8KB)
  __shared__ float g_l[128], b_l[128];
  const int tid = threadIdx.x, lane = tid & 63, w = tid >> 6;
  const int hi = lane >> 5, l31 = lane & 31;
  const int wr = w >> 1, wc = w & 1;

  const float* gsrc = ((conv < 3) ? sg : tg) + slot*384 + row0;
  const float* bsrc = ((conv < 3) ? sb : tb_) + slot*384 + row0;
  if (tid < 128) g_l[tid] = gsrc[tid];
  else b_l[tid - 128] = bsrc[tid - 128];
  __syncthreads();                      // g_l/b_l visible; no vmem in flight yet

  // 16 staging sets per k-step (A: s=v*4+rb in [0,8); B: 8 + v*4+cb), 4/wave
  const uint8_t* gp[4]; uint32_t loff[4];
  #pragma unroll
  for (int j = 0; j < 4; j++) {
    const int s = w*4 + j;
    if (s < 8) {
      const int v = s >> 2, rb = s & 3;
      gp[j] = (const uint8_t*)(Wsplit + ((size_t)(conv*2 + v)*384 + row0 + rb*32 + l31)*384 + 8*hi);
      loff[j] = (uint32_t)(s*1024 + lane*16);
    } else {
      const int s2 = s - 8, v = s2 >> 2, cb = s2 & 3;
      gp[j] = (const uint8_t*)(XT + (((size_t)(inp*2 + v)*40 + tb_i)*384 + n0 + cb*32 + l31)*384 + 8*hi);
      loff[j] = (uint32_t)(8192 + s2*1024 + lane*16);
    }
  }

  f32x16 accA[2][2], accB[2][2];
  #pragma unroll
  for (int i = 0; i < 2; i++)
    #pragma unroll
    for (int j = 0; j < 2; j++)
      #pragma unroll
      for (int e = 0; e < 16; e++) { accA[i][j][e] = 0.0f; accB[i][j][e] = 0.0f; }

  // prologue: stage ks=0 -> buf0, ks=1 -> buf1 (8 loads in flight per wave)
  #pragma unroll
  for (int j = 0; j < 4; j++) gload_lds16(gp[j], &lds[0*16384 + loff[j]]);
  #pragma unroll
  for (int j = 0; j < 4; j++) gload_lds16(gp[j] + 32, &lds[1*16384 + loff[j]]);

  int ib = 0;                            // buffer holding k-step ks
  for (int ks = 0; ks < 24; ks++) {
    if (ks < 23) { VMCNT(4); } else { VMCNT(0); }   // wait stage(ks), keep stage(ks+1) in flight
    SBAR();
    SCHEDB();
    if (ks < 22) {                       // restage buffer read at iter ks-1
      int is = ib + 2; if (is >= 3) is -= 3;
      uint8_t* nb = &lds[is * 16384];
      #pragma unroll
      for (int j = 0; j < 4; j++)
        gload_lds16(gp[j] + (size_t)(ks + 2) * 32, &nb[loff[j]]);
    }
    const uint8_t* buf = &lds[ib * 16384];
    f16x8 af[2][2], bfv[2][2];
    #pragma unroll
    for (int i = 0; i < 2; i++)
      #pragma unroll
      for (int v = 0; v < 2; v++) {
        af[i][v]  = *(const f16x8*)(buf + (v*4 + wr*2 + i)*1024 + lane*16);
        bfv[i][v] = *(const f16x8*)(buf + 8192 + (v*4 + wc*2 + i)*1024 + lane*16);
      }
    __builtin_amdgcn_s_setprio(1);
    #pragma unroll
    for (int i = 0; i < 2; i++)
      #pragma unroll
      for (int j = 0; j < 2; j++) {
        accA[i][j] = __builtin_amdgcn_mfma_f32_32x32x16_f16(af[i][0], bfv[j][0], accA[i][j], 0, 0, 0);
        accB[i][j] = __builtin_amdgcn_mfma_f32_32x32x16_f16(af[i][0], bfv[j][1], accB[i][j], 0, 0, 0);
        accB[i][j] = __builtin_amdgcn_mfma_f32_32x32x16_f16(af[i][1], bfv[j][0], accB[i][j], 0, 0, 0);
      }
    __builtin_amdgcn_s_setprio(0);
    ib = (ib == 2) ? 0 : ib + 1;
  }

  uint32_t* Pout;
  switch (conv) {
    case 0: Pout = PSq; break;
    case 1: Pout = PSk; break;
    case 2: Pout = PSv; break;
    case 3: Pout = PTq; break;
    case 4: Pout = PTk; break;
    default: Pout = PTv; break;
  }
  #pragma unroll
  for (int i = 0; i < 2; i++) {
    const int rb = wr*2 + i;
    const int h = (row0 >> 5) + rb;
    #pragma unroll
    for (int j = 0; j < 2; j++) {
      const int cb = wc*2 + j;
      uint32_t u = 0;
      #pragma unroll
      for (int reg = 0; reg < 16; reg++) {
        const int row = (reg & 3) + 8*(reg >> 2) + 4*hi;
        const float acc = fmaf(accB[i][j][reg], INV2048, accA[i][j][reg]);
        const float z = acc * g_l[rb*32 + row] + b_l[rb*32 + row];
        u |= (z >= 2.0f ? 1u : 0u) << row;
      }
      u |= (uint32_t)__shfl_xor((int)u, 32, 64);
      if (hi == 0) {
        const int ncol = n0 + cb*32 + l31;
        if (conv < 3) Pout[((size_t)tb_i*12 + h)*384 + ncol] = u;
        else          Pout[(((size_t)b*12 + h)*10 + t)*384 + ncol] = u;
      }
    }
  }
}

// ===========================================================================
// conv4 via MFMA: 2-product fp16 GEMM (binary fp16 RHS, exact) + BN + LIF.
// Same counted-vmcnt 3-buffer pipeline (3 sets/wave -> vmcnt(3)).
// Grid: 1-D 360 XCD-swizzled.
// ===========================================================================
__global__ __launch_bounds__(256) void conv4_mfma(
    const uint16_t* __restrict__ Wsplit, const uint16_t* __restrict__ BT,
    const float* __restrict__ g, const float* __restrict__ bsh,
    uint8_t* __restrict__ Sout, int wconv)
{
  const int bid = blockIdx.x;
  const int xcd = bid & 7, pos = bid >> 3;     // pos in [0,45)
  const int xi = pos / 5;                      // 0..8
  const int tb_i = xcd * 5 + (pos % 5);        // 0..39
  const int mtile = xi / 3, ntile = xi % 3;
  const int row0 = mtile * 128, n0 = ntile * 128;

  __shared__ uint8_t lds[36864];                 // 3 x (A 8KB + B 4KB)
  __shared__ float g_l[128], b_l[128];
  const int tid = threadIdx.x, lane = tid & 63, w = tid >> 6;
  const int hi = lane >> 5, l31 = lane & 31;
  const int wr = w >> 1, wc = w & 1;

  if (tid < 128) g_l[tid] = g[row0 + tid];
  else b_l[tid - 128] = bsh[row0 + tid - 128];
  __syncthreads();

  const uint8_t* gp[3]; uint32_t loff[3];
  #pragma unroll
  for (int j = 0; j < 3; j++) {
    const int s = w*3 + j;                     // 0..11
    if (s < 8) {
      const int v = s >> 2, rb = s & 3;
      gp[j] = (const uint8_t*)(Wsplit + ((size_t)(wconv*2 + v)*384 + row0 + rb*32 + l31)*384 + 8*hi);
      loff[j] = (uint32_t)(s*1024 + lane*16);
    } else {
      const int cb = s - 8;
      gp[j] = (const uint8_t*)(BT + ((size_t)tb_i*384 + n0 + cb*32 + l31)*384 + 8*hi);
      loff[j] = (uint32_t)(8192 + cb*1024 + lane*16);
    }
  }

  f32x16 accA[2][2], accB[2][2];
  #pragma unroll
  for (int i = 0; i < 2; i++)
    #pragma unroll
    for (int j = 0; j < 2; j++)
      #pragma unroll
      for (int e = 0; e < 16; e++) { accA[i][j][e] = 0.0f; accB[i][j][e] = 0.0f; }

  #pragma unroll
  for (int j = 0; j < 3; j++) gload_lds16(gp[j], &lds[0*12288 + loff[j]]);
  #pragma unroll
  for (int j = 0; j < 3; j++) gload_lds16(gp[j] + 32, &lds[1*12288 + loff[j]]);

  int ib = 0;
  for (int ks = 0; ks < 24; ks++) {
    if (ks < 23) { VMCNT(3); } else { VMCNT(0); }
    SBAR();
    SCHEDB();
    if (ks < 22) {
      int is = ib + 2; if (is >= 3) is -= 3;
      uint8_t* nb = &lds[is * 12288];
      #pragma unroll
      for (int j = 0; j < 3; j++)
        gload_lds16(gp[j] + (size_t)(ks + 2) * 32, &nb[loff[j]]);
    }
    const uint8_t* buf = &lds[ib * 12288];
    f16x8 af[2][2], bfv[2];
    #pragma unroll
    for (int i = 0; i < 2; i++) {
      #pragma unroll
      for (int v = 0; v < 2; v++)
        af[i][v] = *(const f16x8*)(buf + (v*4 + wr*2 + i)*1024 + lane*16);
      bfv[i] = *(const f16x8*)(buf + 8192 + (wc*2 + i)*1024 + lane*16);
    }
    __builtin_amdgcn_s_setprio(1);
    #pragma unroll
    for (int i = 0; i < 2; i++)
      #pragma unroll
      for (int j = 0; j < 2; j++) {
        accA[i][j] = __builtin_amdgcn_mfma_f32_32x32x16_f16(af[i][0], bfv[j], accA[i][j], 0, 0, 0);
        accB[i][j] = __builtin_amdgcn_mfma_f32_32x32x16_f16(af[i][1], bfv[j], accB[i][j], 0, 0, 0);
      }
    __builtin_amdgcn_s_setprio(0);
    ib = (ib == 2) ? 0 : ib + 1;
  }

  uint8_t* outb = Sout + (size_t)tb_i * CN_;
  #pragma unroll
  for (int i = 0; i < 2; i++) {
    const int rb = wr*2 + i;
    #pragma unroll
    for (int j = 0; j < 2; j++) {
      const int cb = wc*2 + j;
      const int n = n0 + cb*32 + l31;
      #pragma unroll
      for (int reg = 0; reg < 16; reg++) {
        const int row = (reg & 3) + 8*(reg >> 2) + 4*hi;
        const int oc = row0 + rb*32 + row;
        const float acc = fmaf(accB[i][j][reg], INV2048, accA[i][j][reg]);
        const float z = acc * g_l[rb*32 + row] + b_l[rb*32 + row];
        outb[(size_t)oc*384 + n] = (z >= 2.0f) ? 1 : 0;
      }
    }
  }
}

// ===========================================================================
// Spatial attention (exact ints): popcount k^T v, o = q(k^T v); spike=(o>=8).
// Output fp16 transposed BspT[tb][n][c]  (1.0h = 0x3C00).
// ===========================================================================
__global__ __launch_bounds__(384) void attn_spatial(
    const uint32_t* __restrict__ PSq, const uint32_t* __restrict__ PSk,
    const uint32_t* __restrict__ PSv, uint16_t* __restrict__ BspT)
{
  const int blk = blockIdx.x;                 // 0..479
  const int h = blk % 12, tb = blk / 12;
  const size_t pbase = ((size_t)tb*12 + h) * 384;

  __shared__ uint32_t qb[384], kb[384], vb[384];
  __shared__ uint32_t knT[32][12], vnT[32][12];
  __shared__ int ktv[32][33];
  const int tid = threadIdx.x;

  qb[tid] = PSq[pbase + tid];
  kb[tid] = PSk[pbase + tid];
  vb[tid] = PSv[pbase + tid];
  __syncthreads();

  {  // column-packed transposes
    const int i = tid & 31, wg = tid >> 5;
    uint32_t kk = 0, vv = 0;
    #pragma unroll
    for (int j = 0; j < 32; j++) {
      kk |= ((kb[wg*32 + j] >> i) & 1u) << j;
      vv |= ((vb[wg*32 + j] >> i) & 1u) << j;
    }
    knT[i][wg] = kk; vnT[i][wg] = vv;
  }
  __syncthreads();

  if (tid < 256) {  // ktv[i][j] = sum_n k[n,i] v[n,j]
    const int i = tid >> 3, j0 = (tid & 7) * 4;
    #pragma unroll
    for (int jj = 0; jj < 4; jj++) {
      int s = 0;
      #pragma unroll
      for (int wg = 0; wg < 12; wg++) s += __popc(knT[i][wg] & vnT[j0 + jj][wg]);
      ktv[i][j0 + jj] = s;
    }
  }
  __syncthreads();

  const int n = tid;
  uint32_t q = qb[n];
  int o[32];
  #pragma unroll
  for (int dd = 0; dd < 32; dd++) o[dd] = 0;
  while (q) {
    const int i = __ffs(q) - 1; q &= q - 1;
    #pragma unroll
    for (int dd = 0; dd < 32; dd++) o[dd] += ktv[i][dd];
  }
  uint16_t rowv[32];
  #pragma unroll
  for (int dd = 0; dd < 32; dd++) rowv[dd] = (o[dd] >= 8) ? 0x3C00 : 0;
  uint4* dst = (uint4*)(BspT + ((size_t)tb*384 + n)*384 + h*32);
  const uint4* s = (const uint4*)rowv;
  dst[0] = s[0]; dst[1] = s[1]; dst[2] = s[2]; dst[3] = s[3];
}

// Temporal attention (exact ints) -> fp16 transposed BtpT[tb2][n][c2].
__global__ __launch_bounds__(384) void attn_temporal(
    const uint32_t* __restrict__ PTq, const uint32_t* __restrict__ PTk,
    const uint32_t* __restrict__ PTv, uint16_t* __restrict__ BtpT)
{
  const int n = threadIdx.x;
  const int h = blockIdx.x, b = blockIdx.y, t = blockIdx.z;
  const size_t base = ((size_t)b*12 + h) * 10 * 384 + n;

  const uint32_t q = PTq[base + (size_t)t*384];
  uint32_t kb[10], vb[10];
  #pragma unroll
  for (int s = 0; s < 10; s++) {
    kb[s] = PTk[base + (size_t)s*384];
    vb[s] = PTv[base + (size_t)s*384];
  }

  int o[32];
  #pragma unroll
  for (int dd = 0; dd < 32; dd++) o[dd] = 0;
  #pragma unroll
  for (int s = 0; s < 10; s++) {
    const int a = __popc(q & kb[s]);
    const uint32_t v = vb[s];
    #pragma unroll
    for (int dd = 0; dd < 32; dd++)
      o[dd] += (int)((v >> dd) & 1) * a;
  }
  uint16_t rowv[32];
  #pragma unroll
  for (int dd = 0; dd < 32; dd++) rowv[dd] = (o[dd] >= 8) ? 0x3C00 : 0;
  const int flat = h*320 + t*32;
  const int t2 = flat / 384, c2 = flat % 384;
  uint4* dst = (uint4*)(BtpT + ((size_t)(t2*4 + b)*384 + n)*384 + c2);
  const uint4* s4 = (const uint4*)rowv;
  dst[0] = s4[0]; dst[1] = s4[1]; dst[2] = s4[2]; dst[3] = s4[3];
}

// ===========================================================================
// reductions + final outer product
// ===========================================================================
__global__ __launch_bounds__(256) void reduce_a(const uint8_t* __restrict__ a_spike,
                                                float* __restrict__ a_red)
{
  const int row = blockIdx.x * 4 + (threadIdx.x >> 6);
  const int lane = threadIdx.x & 63;
  const uint8_t* p = a_spike + (size_t)row * 384;
  int s = 0;
  #pragma unroll
  for (int i = 0; i < 6; i++) s += p[lane + i*64];
  #pragma unroll
  for (int off = 32; off; off >>= 1) s += __shfl_down(s, off, 64);
  if (lane == 0) a_red[row] = (float)s * (1.0f / 384.0f);
}

__global__ __launch_bounds__(256) void reduce_b(const uint8_t* __restrict__ bt_spike,
                                                float* __restrict__ b_red)
{
  const int idx = blockIdx.x * 256 + threadIdx.x;
  int s = 0;
  #pragma unroll
  for (int t = 0; t < 10; t++) s += bt_spike[(size_t)t * BCN_ + idx];
  b_red[idx] = (float)s * 0.1f;
}

__global__ __launch_bounds__(256) void final_kernel(const float* __restrict__ a_red,
                                                    const float* __restrict__ b_red,
                                                    float* __restrict__ out)
{
  const int idx = blockIdx.x * 256 + threadIdx.x;
  out[idx] = a_red[idx / 384] * b_red[idx % BCN_];
}

// ===========================================================================
extern "C" void kernel_launch(void* const* d_in, const int* in_sizes, int n_in,
                              void* d_out, int out_size, void* d_ws, size_t ws_size,
                              hipStream_t stream) {
  const float* x  = (const float*)d_in[0];
  const float* y  = (const float*)d_in[1];
  const float* sW = (const float*)d_in[2];
  const float* sg = (const float*)d_in[3];
  const float* sb = (const float*)d_in[4];
  const float* tW = (const float*)d_in[5];
  const float* tg = (const float*)d_in[6];
  const float* tb = (const float*)d_in[7];
  float* out = (float*)d_out;

  uint16_t* XT   = (uint16_t*)d_ws;              // 23,592,960 elems (2 levels)
  uint16_t* Wsp  = XT + 23592960;                // 2,359,296 elems
  uint32_t* PSq  = (uint32_t*)(Wsp + 2359296);
  uint32_t* PSk  = PSq + PKN_;
  uint32_t* PSv  = PSk + PKN_;
  uint32_t* PTq  = PSv + PKN_;
  uint32_t* PTk  = PTq + PKN_;
  uint32_t* PTv  = PTk + PKN_;
  uint16_t* BspT = (uint16_t*)(PTv + PKN_);      // 5,898,240 elems
  uint16_t* BtpT = BspT + 5898240;
  uint8_t* a_spike  = (uint8_t*)(BtpT + 5898240);
  uint8_t* bt_spike = a_spike + TBCN_;
  float* a_red = (float*)(bt_spike + TBCN_);
  float* b_red = a_red + 15360;

  wsplit_kernel<<<4608, 256, 0, stream>>>(sW, tW, Wsp);
  xsplit_kernel<<<dim3(12, 3, 80), 256, 0, stream>>>(x, y, XT);
  conv1_mfma<<<2160, 256, 0, stream>>>(Wsp, XT, sg, sb, tg, tb,
                                       PSq, PSk, PSv, PTq, PTk, PTv);
  attn_spatial<<<480, 384, 0, stream>>>(PSq, PSk, PSv, BspT);
  attn_temporal<<<dim3(12, 4, 10), 384, 0, stream>>>(PTq, PTk, PTv, BtpT);
  conv4_mfma<<<360, 256, 0, stream>>>(Wsp, BspT, sg + 3*384, sb + 3*384, a_spike, 6);
  conv4_mfma<<<360, 256, 0, stream>>>(Wsp, BtpT, tg + 3*384, tb + 3*384, bt_spike, 7);
  reduce_a<<<3840, 256, 0, stream>>>(a_spike, a_red);
  reduce_b<<<2304, 256, 0, stream>>>(bt_spike, b_red);
  final_kernel<<<23040, 256, 0, stream>>>(a_red, b_red, out);
}

// Round 8
// 319.385 us; speedup vs baseline: 1.3360x; 1.3360x over previous
//
#include <hip/hip_runtime.h>
#include <stdint.h>

#define T_ 10
#define B_ 4
#define C_ 384
#define N_ 384
#define H_ 12
#define CN_ 147456      // C_*N_
#define TBCN_ 5898240   // T_*B_*C_*N_
#define BCN_ 589824     // B_*C_*N_
#define PKN_ 184320     // 40*12*384  (packed words per q/k/v array)

typedef _Float16 f16x8 __attribute__((ext_vector_type(8)));
typedef float f32x16 __attribute__((ext_vector_type(16)));

#define VMCNT(N) asm volatile("s_waitcnt vmcnt(" #N ")" ::: "memory")
#define SBAR()   __builtin_amdgcn_s_barrier()
#define SCHEDB() __builtin_amdgcn_sched_barrier(0)

#define INV2048 4.8828125e-4f
#define H_MIN_NORMAL 6.103515625e-05f

// Exact 2-level fp16 split: v = H0 + H1*2^-11, H1 stored pre-scaled by 2^11
// (never denormal for these magnitudes). |v| < fp16-min-normal goes entirely
// into the scaled level, so MFMA denormal behavior is never exercised.
__device__ inline void split2h(float v, uint16_t* h0, uint16_t* h1) {
  _Float16 H0 = (fabsf(v) < H_MIN_NORMAL) ? (_Float16)0.0f : (_Float16)v;  // RNE
  const float r = (v - (float)H0) * 2048.0f;
  _Float16 H1 = (_Float16)r;
  *h0 = __builtin_bit_cast(uint16_t, H0);
  *h1 = __builtin_bit_cast(uint16_t, H1);
}

// async global->LDS, 16B per lane; LDS dest must be wave-uniform base + lane*16
__device__ inline void gload_lds16(const void* g, void* l) {
  __builtin_amdgcn_global_load_lds(
      (const __attribute__((address_space(1))) uint32_t*)g,
      (__attribute__((address_space(3))) uint32_t*)l, 16, 0, 0);
}

// ===========================================================================
// Weight split: 8 convs (Sq,Sk,Sv,Tq,Tk,Tv,Sproj,Tproj) -> 2 fp16 levels
// Wsplit[(conv*2+v)*147456 + oc*384 + k].
// ===========================================================================
__global__ __launch_bounds__(256) void wsplit_kernel(
    const float* __restrict__ sW, const float* __restrict__ tW,
    uint16_t* __restrict__ Wsplit)
{
  const int idx = blockIdx.x * 256 + threadIdx.x;   // < 8*147456
  const int conv = idx / 147456, rem = idx % 147456;
  const float* src;
  switch (conv) {
    case 0: src = sW;          break;
    case 1: src = sW + CN_;    break;
    case 2: src = sW + 2*CN_;  break;
    case 3: src = tW;          break;
    case 4: src = tW + CN_;    break;
    case 5: src = tW + 2*CN_;  break;
    case 6: src = sW + 3*CN_;  break;
    default: src = tW + 3*CN_; break;
  }
  uint16_t h0, h1;
  split2h(src[rem], &h0, &h1);
  Wsplit[(size_t)(conv*2 + 0)*147456 + rem] = h0;
  Wsplit[(size_t)(conv*2 + 1)*147456 + rem] = h1;
}

// Split x,y into 2 fp16 levels, TRANSPOSED: XT[inp][v][tb][n][k].
__global__ __launch_bounds__(256) void xsplit_kernel(
    const float* __restrict__ x, const float* __restrict__ y,
    uint16_t* __restrict__ XT)
{
  const int kt = blockIdx.x;            // 0..11 -> k0
  const int nt = blockIdx.y;            // 0..2  -> n0
  const int z  = blockIdx.z;            // 0..79: inp*40+tb
  const int inp = z / 40, tb = z % 40;
  const float* in = (inp ? y : x) + (size_t)tb * CN_;
  const int k0 = kt * 32, n0 = nt * 128;
  __shared__ uint16_t Ls[2][32][132];
  const int tid = threadIdx.x;
  const int kr = tid >> 3, nc = (tid & 7) * 16;
  #pragma unroll
  for (int q = 0; q < 4; q++) {
    const float4 f = *(const float4*)(in + (size_t)(k0 + kr)*384 + n0 + nc + q*4);
    const float vv[4] = {f.x, f.y, f.z, f.w};
    #pragma unroll
    for (int e = 0; e < 4; e++) {
      uint16_t h0, h1;
      split2h(vv[e], &h0, &h1);
      Ls[0][kr][nc + q*4 + e] = h0;
      Ls[1][kr][nc + q*4 + e] = h1;
    }
  }
  __syncthreads();
  {
    const int v = tid >> 7, n = tid & 127;    // 256 threads = 2 levels x 128 n
    uint16_t tmp[32];
    #pragma unroll
    for (int k = 0; k < 32; k++) tmp[k] = Ls[v][k][n];
    uint4* dst = (uint4*)(XT + (((size_t)(inp*2 + v)*40 + tb)*384 + (n0 + n))*384 + k0);
    const uint4* s = (const uint4*)tmp;
    dst[0] = s[0]; dst[1] = s[1]; dst[2] = s[2]; dst[3] = s[3];
  }
}

// ===========================================================================
// conv1 via MFMA: 6 convs, 3-product 2-level-fp16 GEMM + BN + LIF ->
// bit-packed spikes. 128x128 tile, EIGHT waves (512 thr), per-wave 64x32
// (acc = 64 VGPR -> 4 waves/SIMD with launch_bounds(512,4)). BK=16,
// 3-buffer counted-vmcnt pipeline (T3+T4) + setprio (T5), XCD swizzle (T1).
// accA = X0W0; accB = X0W1s + X1sW0; z = (accA + accB/2048)*g + b.
// ===========================================================================
__global__ __launch_bounds__(512, 4) void conv1_mfma(
    const uint16_t* __restrict__ Wsplit, const uint16_t* __restrict__ XT,
    const float* __restrict__ sg, const float* __restrict__ sb,
    const float* __restrict__ tg, const float* __restrict__ tb_,
    uint32_t* __restrict__ PSq, uint32_t* __restrict__ PSk, uint32_t* __restrict__ PSv,
    uint32_t* __restrict__ PTq, uint32_t* __restrict__ PTk, uint32_t* __restrict__ PTv)
{
  // ---- XCD-aware bijective remap (2160 = 8 XCD x 270; 270 = 3 ntile x 18 cm x 5 tb) ----
  const int bid = blockIdx.x;
  const int xcd = bid & 7, pos = bid >> 3;     // pos in [0,270)
  const int ntile = pos / 90;
  const int r = pos % 90;
  const int cm = r / 5;                        // (conv,mt) in [0,18)
  const int tb_i = xcd * 5 + (r % 5);          // [0,40)
  const int conv = cm / 3, row0 = (cm % 3) * 128, n0 = ntile * 128;
  const int t = tb_i >> 2, b = tb_i & 3;
  const int slot = (conv < 3) ? conv : conv - 3;
  const int inp = (conv == 0 || conv == 3) ? 0 : 1;

  __shared__ uint8_t lds[49152];                 // 3 x (A 8KB + B 8KB)
  __shared__ float g_l[128], b_l[128];
  const int tid = threadIdx.x, lane = tid & 63, w = tid >> 6;   // w 0..7
  const int hi = lane >> 5, l31 = lane & 31;
  const int wr = w >> 2, wc = w & 3;             // wr 0..1 (64-row half), wc 0..3 (32-col)

  const float* gsrc = ((conv < 3) ? sg : tg) + slot*384 + row0;
  const float* bsrc = ((conv < 3) ? sb : tb_) + slot*384 + row0;
  if (tid < 128) g_l[tid] = gsrc[tid];
  else if (tid < 256) b_l[tid - 128] = bsrc[tid - 128];
  __syncthreads();                      // params visible; no vmem in flight yet

  // 16 staging sets per k-step (A: s in [0,8): v*4+rb; B: s-8 = v*4+cb), 2/wave
  const uint8_t* gp[2]; uint32_t loff[2];
  #pragma unroll
  for (int j = 0; j < 2; j++) {
    const int s = w*2 + j;
    if (s < 8) {
      const int v = s >> 2, rb = s & 3;
      gp[j] = (const uint8_t*)(Wsplit + ((size_t)(conv*2 + v)*384 + row0 + rb*32 + l31)*384 + 8*hi);
    } else {
      const int s2 = s - 8, v = s2 >> 2, cb = s2 & 3;
      gp[j] = (const uint8_t*)(XT + (((size_t)(inp*2 + v)*40 + tb_i)*384 + n0 + cb*32 + l31)*384 + 8*hi);
    }
    loff[j] = (uint32_t)(s*1024 + lane*16);
  }

  f32x16 accA[2], accB[2];
  #pragma unroll
  for (int i = 0; i < 2; i++)
    #pragma unroll
    for (int e = 0; e < 16; e++) { accA[i][e] = 0.0f; accB[i][e] = 0.0f; }

  // prologue: stage ks=0 -> buf0, ks=1 -> buf1 (4 loads in flight per wave)
  #pragma unroll
  for (int j = 0; j < 2; j++) gload_lds16(gp[j], &lds[0*16384 + loff[j]]);
  #pragma unroll
  for (int j = 0; j < 2; j++) gload_lds16(gp[j] + 32, &lds[1*16384 + loff[j]]);

  int ib = 0;                            // buffer holding k-step ks
  for (int ks = 0; ks < 24; ks++) {
    if (ks < 23) { VMCNT(2); } else { VMCNT(0); }   // wait stage(ks); stage(ks+1) stays in flight
    SBAR();
    SCHEDB();
    if (ks < 22) {                       // restage buffer consumed at iter ks-1
      int is = ib + 2; if (is >= 3) is -= 3;
      uint8_t* nb = &lds[is * 16384];
      #pragma unroll
      for (int j = 0; j < 2; j++)
        gload_lds16(gp[j] + (size_t)(ks + 2) * 32, &nb[loff[j]]);
    }
    const uint8_t* buf = &lds[ib * 16384];
    f16x8 af[2][2], bfv[2];
    #pragma unroll
    for (int i = 0; i < 2; i++)
      #pragma unroll
      for (int v = 0; v < 2; v++)
        af[i][v] = *(const f16x8*)(buf + (v*4 + wr*2 + i)*1024 + lane*16);
    #pragma unroll
    for (int v = 0; v < 2; v++)
      bfv[v] = *(const f16x8*)(buf + 8192 + (v*4 + wc)*1024 + lane*16);
    __builtin_amdgcn_s_setprio(1);
    #pragma unroll
    for (int i = 0; i < 2; i++) {
      accA[i] = __builtin_amdgcn_mfma_f32_32x32x16_f16(af[i][0], bfv[0], accA[i], 0, 0, 0);
      accB[i] = __builtin_amdgcn_mfma_f32_32x32x16_f16(af[i][0], bfv[1], accB[i], 0, 0, 0);
      accB[i] = __builtin_amdgcn_mfma_f32_32x32x16_f16(af[i][1], bfv[0], accB[i], 0, 0, 0);
    }
    __builtin_amdgcn_s_setprio(0);
    ib = (ib == 2) ? 0 : ib + 1;
  }

  uint32_t* Pout;
  switch (conv) {
    case 0: Pout = PSq; break;
    case 1: Pout = PSk; break;
    case 2: Pout = PSv; break;
    case 3: Pout = PTq; break;
    case 4: Pout = PTk; break;
    default: Pout = PTv; break;
  }
  #pragma unroll
  for (int i = 0; i < 2; i++) {
    const int rb = wr*2 + i;
    const int h = (row0 >> 5) + rb;
    uint32_t u = 0;
    #pragma unroll
    for (int reg = 0; reg < 16; reg++) {
      const int row = (reg & 3) + 8*(reg >> 2) + 4*hi;
      const float acc = fmaf(accB[i][reg], INV2048, accA[i][reg]);
      const float z = acc * g_l[rb*32 + row] + b_l[rb*32 + row];
      u |= (z >= 2.0f ? 1u : 0u) << row;
    }
    u |= (uint32_t)__shfl_xor((int)u, 32, 64);
    if (hi == 0) {
      const int ncol = n0 + wc*32 + l31;
      if (conv < 3) Pout[((size_t)tb_i*12 + h)*384 + ncol] = u;
      else          Pout[(((size_t)b*12 + h)*10 + t)*384 + ncol] = u;
    }
  }
}

// ===========================================================================
// conv4 via MFMA: 2-product fp16 GEMM (binary fp16 RHS, exact) + BN + LIF.
// Same 8-wave/512-thr structure; waves 0-5 stage 2 sets each, 6-7 none
// (their vm-counter is 0 so uniform VMCNT(2) is safe). Grid: 360 XCD-swizzled.
// ===========================================================================
__global__ __launch_bounds__(512, 4) void conv4_mfma(
    const uint16_t* __restrict__ Wsplit, const uint16_t* __restrict__ BT,
    const float* __restrict__ g, const float* __restrict__ bsh,
    uint8_t* __restrict__ Sout, int wconv)
{
  const int bid = blockIdx.x;
  const int xcd = bid & 7, pos = bid >> 3;     // pos in [0,45)
  const int xi = pos / 5;                      // 0..8
  const int tb_i = xcd * 5 + (pos % 5);        // 0..39
  const int mtile = xi / 3, ntile = xi % 3;
  const int row0 = mtile * 128, n0 = ntile * 128;

  __shared__ uint8_t lds[36864];                 // 3 x (A 8KB + B 4KB)
  __shared__ float g_l[128], b_l[128];
  const int tid = threadIdx.x, lane = tid & 63, w = tid >> 6;
  const int hi = lane >> 5, l31 = lane & 31;
  const int wr = w >> 2, wc = w & 3;

  if (tid < 128) g_l[tid] = g[row0 + tid];
  else if (tid < 256) b_l[tid - 128] = bsh[row0 + tid - 128];
  __syncthreads();

  // 12 staging sets (A: 8 = v*4+rb; B: 4 = cb at 8K+). waves 0-5: 2 sets each.
  const uint8_t* gp[2]; uint32_t loff[2];
  const bool stager = (w < 6);
  #pragma unroll
  for (int j = 0; j < 2; j++) {
    const int s = w*2 + j;                     // 0..11 for stagers
    if (s < 8) {
      const int v = s >> 2, rb = s & 3;
      gp[j] = (const uint8_t*)(Wsplit + ((size_t)(wconv*2 + v)*384 + row0 + rb*32 + l31)*384 + 8*hi);
    } else {
      const int cb = s - 8;
      gp[j] = (const uint8_t*)(BT + ((size_t)tb_i*384 + n0 + cb*32 + l31)*384 + 8*hi);
    }
    loff[j] = (uint32_t)(s*1024 + lane*16);
  }

  f32x16 accA[2], accB[2];
  #pragma unroll
  for (int i = 0; i < 2; i++)
    #pragma unroll
    for (int e = 0; e < 16; e++) { accA[i][e] = 0.0f; accB[i][e] = 0.0f; }

  if (stager) {
    #pragma unroll
    for (int j = 0; j < 2; j++) gload_lds16(gp[j], &lds[0*12288 + loff[j]]);
    #pragma unroll
    for (int j = 0; j < 2; j++) gload_lds16(gp[j] + 32, &lds[1*12288 + loff[j]]);
  }

  int ib = 0;
  for (int ks = 0; ks < 24; ks++) {
    if (ks < 23) { VMCNT(2); } else { VMCNT(0); }
    SBAR();
    SCHEDB();
    if (ks < 22 && stager) {
      int is = ib + 2; if (is >= 3) is -= 3;
      uint8_t* nb = &lds[is * 12288];
      #pragma unroll
      for (int j = 0; j < 2; j++)
        gload_lds16(gp[j] + (size_t)(ks + 2) * 32, &nb[loff[j]]);
    }
    const uint8_t* buf = &lds[ib * 12288];
    f16x8 af[2][2], bfv;
    #pragma unroll
    for (int i = 0; i < 2; i++)
      #pragma unroll
      for (int v = 0; v < 2; v++)
        af[i][v] = *(const f16x8*)(buf + (v*4 + wr*2 + i)*1024 + lane*16);
    bfv = *(const f16x8*)(buf + 8192 + wc*1024 + lane*16);
    __builtin_amdgcn_s_setprio(1);
    #pragma unroll
    for (int i = 0; i < 2; i++) {
      accA[i] = __builtin_amdgcn_mfma_f32_32x32x16_f16(af[i][0], bfv, accA[i], 0, 0, 0);
      accB[i] = __builtin_amdgcn_mfma_f32_32x32x16_f16(af[i][1], bfv, accB[i], 0, 0, 0);
    }
    __builtin_amdgcn_s_setprio(0);
    ib = (ib == 2) ? 0 : ib + 1;
  }

  uint8_t* outb = Sout + (size_t)tb_i * CN_;
  #pragma unroll
  for (int i = 0; i < 2; i++) {
    const int rb = wr*2 + i;
    const int n = n0 + wc*32 + l31;
    #pragma unroll
    for (int reg = 0; reg < 16; reg++) {
      const int row = (reg & 3) + 8*(reg >> 2) + 4*hi;
      const int oc = row0 + rb*32 + row;
      const float acc = fmaf(accB[i][reg], INV2048, accA[i][reg]);
      const float z = acc * g_l[rb*32 + row] + b_l[rb*32 + row];
      outb[(size_t)oc*384 + n] = (z >= 2.0f) ? 1 : 0;
    }
  }
}

// ===========================================================================
// Spatial attention (exact ints): popcount k^T v, o = q(k^T v); spike=(o>=8).
// Output fp16 transposed BspT[tb][n][c]  (1.0h = 0x3C00).
// ===========================================================================
__global__ __launch_bounds__(384) void attn_spatial(
    const uint32_t* __restrict__ PSq, const uint32_t* __restrict__ PSk,
    const uint32_t* __restrict__ PSv, uint16_t* __restrict__ BspT)
{
  const int blk = blockIdx.x;                 // 0..479
  const int h = blk % 12, tb = blk / 12;
  const size_t pbase = ((size_t)tb*12 + h) * 384;

  __shared__ uint32_t qb[384], kb[384], vb[384];
  __shared__ uint32_t knT[32][12], vnT[32][12];
  __shared__ int ktv[32][33];
  const int tid = threadIdx.x;

  qb[tid] = PSq[pbase + tid];
  kb[tid] = PSk[pbase + tid];
  vb[tid] = PSv[pbase + tid];
  __syncthreads();

  {  // column-packed transposes
    const int i = tid & 31, wg = tid >> 5;
    uint32_t kk = 0, vv = 0;
    #pragma unroll
    for (int j = 0; j < 32; j++) {
      kk |= ((kb[wg*32 + j] >> i) & 1u) << j;
      vv |= ((vb[wg*32 + j] >> i) & 1u) << j;
    }
    knT[i][wg] = kk; vnT[i][wg] = vv;
  }
  __syncthreads();

  if (tid < 256) {  // ktv[i][j] = sum_n k[n,i] v[n,j]
    const int i = tid >> 3, j0 = (tid & 7) * 4;
    #pragma unroll
    for (int jj = 0; jj < 4; jj++) {
      int s = 0;
      #pragma unroll
      for (int wg = 0; wg < 12; wg++) s += __popc(knT[i][wg] & vnT[j0 + jj][wg]);
      ktv[i][j0 + jj] = s;
    }
  }
  __syncthreads();

  const int n = tid;
  uint32_t q = qb[n];
  int o[32];
  #pragma unroll
  for (int dd = 0; dd < 32; dd++) o[dd] = 0;
  while (q) {
    const int i = __ffs(q) - 1; q &= q - 1;
    #pragma unroll
    for (int dd = 0; dd < 32; dd++) o[dd] += ktv[i][dd];
  }
  uint16_t rowv[32];
  #pragma unroll
  for (int dd = 0; dd < 32; dd++) rowv[dd] = (o[dd] >= 8) ? 0x3C00 : 0;
  uint4* dst = (uint4*)(BspT + ((size_t)tb*384 + n)*384 + h*32);
  const uint4* s = (const uint4*)rowv;
  dst[0] = s[0]; dst[1] = s[1]; dst[2] = s[2]; dst[3] = s[3];
}

// Temporal attention (exact ints) -> fp16 transposed BtpT[tb2][n][c2].
__global__ __launch_bounds__(384) void attn_temporal(
    const uint32_t* __restrict__ PTq, const uint32_t* __restrict__ PTk,
    const uint32_t* __restrict__ PTv, uint16_t* __restrict__ BtpT)
{
  const int n = threadIdx.x;
  const int h = blockIdx.x, b = blockIdx.y, t = blockIdx.z;
  const size_t base = ((size_t)b*12 + h) * 10 * 384 + n;

  const uint32_t q = PTq[base + (size_t)t*384];
  uint32_t kb[10], vb[10];
  #pragma unroll
  for (int s = 0; s < 10; s++) {
    kb[s] = PTk[base + (size_t)s*384];
    vb[s] = PTv[base + (size_t)s*384];
  }

  int o[32];
  #pragma unroll
  for (int dd = 0; dd < 32; dd++) o[dd] = 0;
  #pragma unroll
  for (int s = 0; s < 10; s++) {
    const int a = __popc(q & kb[s]);
    const uint32_t v = vb[s];
    #pragma unroll
    for (int dd = 0; dd < 32; dd++)
      o[dd] += (int)((v >> dd) & 1) * a;
  }
  uint16_t rowv[32];
  #pragma unroll
  for (int dd = 0; dd < 32; dd++) rowv[dd] = (o[dd] >= 8) ? 0x3C00 : 0;
  const int flat = h*320 + t*32;
  const int t2 = flat / 384, c2 = flat % 384;
  uint4* dst = (uint4*)(BtpT + ((size_t)(t2*4 + b)*384 + n)*384 + c2);
  const uint4* s4 = (const uint4*)rowv;
  dst[0] = s4[0]; dst[1] = s4[1]; dst[2] = s4[2]; dst[3] = s4[3];
}

// ===========================================================================
// reductions + final outer product
// ===========================================================================
__global__ __launch_bounds__(256) void reduce_a(const uint8_t* __restrict__ a_spike,
                                                float* __restrict__ a_red)
{
  const int row = blockIdx.x * 4 + (threadIdx.x >> 6);
  const int lane = threadIdx.x & 63;
  const uint8_t* p = a_spike + (size_t)row * 384;
  int s = 0;
  #pragma unroll
  for (int i = 0; i < 6; i++) s += p[lane + i*64];
  #pragma unroll
  for (int off = 32; off; off >>= 1) s += __shfl_down(s, off, 64);
  if (lane == 0) a_red[row] = (float)s * (1.0f / 384.0f);
}

__global__ __launch_bounds__(256) void reduce_b(const uint8_t* __restrict__ bt_spike,
                                                float* __restrict__ b_red)
{
  const int idx = blockIdx.x * 256 + threadIdx.x;
  int s = 0;
  #pragma unroll
  for (int t = 0; t < 10; t++) s += bt_spike[(size_t)t * BCN_ + idx];
  b_red[idx] = (float)s * 0.1f;
}

__global__ __launch_bounds__(256) void final_kernel(const float* __restrict__ a_red,
                                                    const float* __restrict__ b_red,
                                                    float* __restrict__ out)
{
  const int idx = blockIdx.x * 256 + threadIdx.x;
  out[idx] = a_red[idx / 384] * b_red[idx % BCN_];
}

// ===========================================================================
extern "C" void kernel_launch(void* const* d_in, const int* in_sizes, int n_in,
                              void* d_out, int out_size, void* d_ws, size_t ws_size,
                              hipStream_t stream) {
  const float* x  = (const float*)d_in[0];
  const float* y  = (const float*)d_in[1];
  const float* sW = (const float*)d_in[2];
  const float* sg = (const float*)d_in[3];
  const float* sb = (const float*)d_in[4];
  const float* tW = (const float*)d_in[5];
  const float* tg = (const float*)d_in[6];
  const float* tb = (const float*)d_in[7];
  float* out = (float*)d_out;

  uint16_t* XT   = (uint16_t*)d_ws;              // 23,592,960 elems (2 levels)
  uint16_t* Wsp  = XT + 23592960;                // 2,359,296 elems
  uint32_t* PSq  = (uint32_t*)(Wsp + 2359296);
  uint32_t* PSk  = PSq + PKN_;
  uint32_t* PSv  = PSk + PKN_;
  uint32_t* PTq  = PSv + PKN_;
  uint32_t* PTk  = PTq + PKN_;
  uint32_t* PTv  = PTk + PKN_;
  uint16_t* BspT = (uint16_t*)(PTv + PKN_);      // 5,898,240 elems
  uint16_t* BtpT = BspT + 5898240;
  uint8_t* a_spike  = (uint8_t*)(BtpT + 5898240);
  uint8_t* bt_spike = a_spike + TBCN_;
  float* a_red = (float*)(bt_spike + TBCN_);
  float* b_red = a_red + 15360;

  wsplit_kernel<<<4608, 256, 0, stream>>>(sW, tW, Wsp);
  xsplit_kernel<<<dim3(12, 3, 80), 256, 0, stream>>>(x, y, XT);
  conv1_mfma<<<2160, 512, 0, stream>>>(Wsp, XT, sg, sb, tg, tb,
                                       PSq, PSk, PSv, PTq, PTk, PTv);
  attn_spatial<<<480, 384, 0, stream>>>(PSq, PSk, PSv, BspT);
  attn_temporal<<<dim3(12, 4, 10), 384, 0, stream>>>(PTq, PTk, PTv, BtpT);
  conv4_mfma<<<360, 512, 0, stream>>>(Wsp, BspT, sg + 3*384, sb + 3*384, a_spike, 6);
  conv4_mfma<<<360, 512, 0, stream>>>(Wsp, BtpT, tg + 3*384, tb + 3*384, bt_spike, 7);
  reduce_a<<<3840, 256, 0, stream>>>(a_spike, a_red);
  reduce_b<<<2304, 256, 0, stream>>>(bt_spike, b_red);
  final_kernel<<<23040, 256, 0, stream>>>(a_red, b_red, out);
}